// Round 1
// 503.593 us; speedup vs baseline: 1.0020x; 1.0020x over previous
//
#include <hip/hip_runtime.h>

// Problem constants (fixed by the reference)
#define BTOT 4096
#define TB   512
#define BD   8
#define BSL  16    // MFMA tile M (R6 lesson: BSL=8 duplicates work chip-wide)

// LDS element map (uint16 elements, 2 B), k-major block layout:
//   A-tile element (row,k) at blk*128 + row*8 + (k&7), blk = k>>3
//   -> lane (q,ln)'s A-frag (row=ln, k=ki*32+q*8+j) = 16 contiguous bytes
//      at (ki*4+q)*128 + ln*8  => ds_read_b128, conflict-free per 8-lane group.
// A0 (h0, K=64): parity p at p*1024                      (els 0..2047)
// A1 (h1, K=64): parity p at 2048 + p*1024               (els 2048..4095)
// ZERO block (always 0, x-frag source for q>0 lanes):    (els 4096..4223)
// XB x chunks (64 t x 16 rows x 8 d, double-buffered):   (els 8192..24575)
#define A0TOG  1024
#define A1BASE 2048
#define A1TOG  1024
#define ZBASE  4096
#define XBASE  8192
#define NLDS   24576   // 48 KiB

typedef __attribute__((ext_vector_type(8))) short  short8;  // MFMA A/B frag
typedef __attribute__((ext_vector_type(4))) float  f32x4;   // MFMA C/D frag

#define MFMA16 __builtin_amdgcn_mfma_f32_16x16x32_bf16

// Raw barrier: wait only LDS ops (ds_write visibility), leave vmcnt
// outstanding so the ph48 global x-prefetch hides across ~14 barriers.
#define BAR() asm volatile("s_waitcnt lgkmcnt(0)\n\ts_barrier" ::: "memory")

static __device__ __forceinline__ unsigned short f2bf(float f) {
    unsigned u = __float_as_uint(f);
    u += 0x7fffu + ((u >> 16) & 1u);
    return (unsigned short)(u >> 16);
}
static __device__ __forceinline__ float bf2f(unsigned short h) {
    return __uint_as_float(((unsigned)h) << 16);
}
static __device__ __forceinline__ unsigned pkbf(float a, float b) {
    unsigned r;  // gfx950 HW packed f32->bf16 (RNE); dest must be VGPR
    asm("v_cvt_pk_bf16_f32 %0, %1, %2" : "=v"(r) : "v"(a), "v"(b));
    return r;
}

// Joint-denominator gate math: 7 trans/unit (5 exp2 + 2 rcp).
// Pre-folded scales: i,f,o rows x -log2(e); g row x 2*log2(e).
static __device__ __forceinline__ void gates4(
    const f32x4 ai, const f32x4 af, const f32x4 ag, const f32x4 ao,
    float cc[4], unsigned hp[2])
{
    float h[4];
    #pragma unroll
    for (int r = 0; r < 4; ++r) {
        const float ei = __builtin_amdgcn_exp2f(ai[r]);
        const float ef = __builtin_amdgcn_exp2f(af[r]);
        const float eg = __builtin_amdgcn_exp2f(ag[r]);
        const float eo = __builtin_amdgcn_exp2f(ao[r]);
        const float Ai = 1.f + ei, Af = 1.f + ef, Ag = 1.f + eg, Ao = 1.f + eo;
        const float P    = Ai * Ag;
        const float numer = cc[r] * P + Af * (eg - 1.f);
        const float rD   = __builtin_amdgcn_rcpf(Af * P);
        cc[r] = numer * rD;
        const float ec = __builtin_amdgcn_exp2f(2.88539008f * cc[r]);
        const float rH = __builtin_amdgcn_rcpf(Ao * (ec + 1.f));
        h[r] = (ec - 1.f) * rH;
    }
    hp[0] = pkbf(h[0], h[1]); hp[1] = pkbf(h[2], h[3]);
}

// MERGED-WAVE DESIGN (this round): 4 waves/block, each wave owns 16 hidden
// cols for BOTH layers. Same per-SIMD issue load as the 8-wave split, but
// L1's MFMAs are independent of L0's gate chain -> ILP fills the stalls the
// lockstep 8-wave version left idle. Shared read: h0(t-1) frags feed both
// L0's recurrence and L1's input (5 ds_read_b128/wave/step instead of 7).
__global__ __launch_bounds__(256, 1) void lstm2_fused(
    const float* __restrict__ x,
    const float* __restrict__ Wih0, const float* __restrict__ Whh0,
    const float* __restrict__ bih0, const float* __restrict__ bhh0,
    const float* __restrict__ Wih1, const float* __restrict__ Whh1,
    const float* __restrict__ bih1, const float* __restrict__ bhh1,
    const float* __restrict__ Wfc,  const float* __restrict__ bfc,
    float* __restrict__ out)
{
    __shared__ __align__(16) unsigned short lds16[NLDS];

    const int tid  = threadIdx.x;
    const int wid  = tid >> 6;           // 4 waves; wave g = cols 16g..16g+15
    const int lane = tid & 63;
    const int q    = lane >> 4;
    const int ln   = lane & 15;
    const int rb   = blockIdx.x * BSL;
    const int jc   = wid * 16 + ln;      // hidden col this lane owns (both layers)

    const float SCI = -1.44269504f;
    const float SCG =  2.88539008f;

    // ---- Weight fragments -> registers (both layers), bf16, scales folded ----
    short8 Bf0[4][3];                    // L0: k 0..63 = Whh0, 64..71 = Wih0
    short8 Bf1[4][4];                    // L1: k 0..63 = Wih1, 64..127 = Whh1
    #pragma unroll
    for (int G = 0; G < 4; ++G) {
        const int n = G * 64 + jc;
        const float sc = (G == 2) ? SCG : SCI;
        #pragma unroll
        for (int ki = 0; ki < 3; ++ki) {
            union { unsigned short u[8]; short8 v; } t;
            #pragma unroll
            for (int j = 0; j < 8; ++j) {
                const int k = ki * 32 + q * 8 + j;
                float wv = 0.0f;
                if (k < 64)      wv = Whh0[n * 64 + k];
                else if (k < 72) wv = Wih0[n * 8 + (k - 64)];
                t.u[j] = f2bf(sc * wv);
            }
            Bf0[G][ki] = t.v;
        }
        #pragma unroll
        for (int ki = 0; ki < 4; ++ki) {
            union { unsigned short u[8]; short8 v; } t;
            #pragma unroll
            for (int j = 0; j < 8; ++j) {
                const int k = ki * 32 + q * 8 + j;
                const float wv = (k < 64) ? Wih1[n * 64 + k]
                                          : Whh1[n * 64 + (k - 64)];
                t.u[j] = f2bf(sc * wv);
            }
            Bf1[G][ki] = t.v;
        }
    }
    f32x4 bias0[4], bias1[4];            // bias as persistent MFMA C-operand
    #pragma unroll
    for (int G = 0; G < 4; ++G) {
        const int n = G * 64 + jc;
        const float sc = (G == 2) ? SCG : SCI;
        const float b0 = sc * (bih0[n] + bhh0[n]);
        const float b1 = sc * (bih1[n] + bhh1[n]);
        bias0[G] = (f32x4){b0, b0, b0, b0};
        bias1[G] = (f32x4){b1, b1, b1, b1};
    }

    // ---- Prologue: zero A0/A1/ZERO, stage x chunk 0 ----
    {
        unsigned* z = (unsigned*)lds16;   // els 0..4223 = 2112 dwords
        #pragma unroll
        for (int i = 0; i < 9; ++i) {
            const int id = tid + i * 256;
            if (id < 2112) z[id] = 0;
        }
    }
    const int srow = tid >> 4, su = tid & 15;  // stager: 32 floats/thread
    {
        const float* gp = x + (size_t)(rb + srow) * (TB * BD) + su * 32;
        float4 v[8];
        #pragma unroll
        for (int i = 0; i < 8; ++i) v[i] = ((const float4*)gp)[i];
        #pragma unroll
        for (int tt = 0; tt < 4; ++tt) {
            uint4 s;
            s.x = pkbf(v[2*tt].x,   v[2*tt].y);   s.y = pkbf(v[2*tt].z,   v[2*tt].w);
            s.z = pkbf(v[2*tt+1].x, v[2*tt+1].y); s.w = pkbf(v[2*tt+1].z, v[2*tt+1].w);
            const int el = XBASE + (su * 4 + tt) * 128 + srow * 8;
            *(uint4*)(lds16 + el) = s;
        }
    }
    __syncthreads();

    // ---- Hoisted ping-pong pointers (element indices), XOR-toggled ----
    const int rbase = q * 128 + ln * 8;                    // A-frag read base
    const int wb    = (jc >> 3) * 128 + q * 32 + (jc & 7); // h-write base
    const int ln8   = ln * 8;
    const int zaddr = ZBASE + ln8;       // q>0 x-frag source (always zero)
    int rdA  = rbase;                    // h0(t-1): read by BOTH layers
    int wr0  = A0TOG + wb;               // h0(t) -> other parity
    int rdH1 = A1BASE + rbase;           // h1(t1-1)
    int wrH1 = A1BASE + A1TOG + wb;      // h1(t1) -> other parity

    float cc0[4] = {0.f, 0.f, 0.f, 0.f};
    float cc1[4] = {0.f, 0.f, 0.f, 0.f};
    float4 px[8];                        // x-chunk global prefetch registers

    // ---- Peeled it=0: L0 only (h0(-1)=h1(-1)=0) ----
    {
        const short8 a0 = *(const short8*)(lds16 + rdA);
        const short8 a1 = *(const short8*)(lds16 + rdA + 512);
        const int xaddr = (q == 0) ? (XBASE + 0 + ln8) : zaddr;
        const short8 a2 = *(const short8*)(lds16 + xaddr);
        f32x4 ai = MFMA16(a0, Bf0[0][0], bias0[0], 0, 0, 0);
        f32x4 af = MFMA16(a0, Bf0[1][0], bias0[1], 0, 0, 0);
        f32x4 ag = MFMA16(a0, Bf0[2][0], bias0[2], 0, 0, 0);
        f32x4 ao = MFMA16(a0, Bf0[3][0], bias0[3], 0, 0, 0);
        ai = MFMA16(a1, Bf0[0][1], ai, 0, 0, 0);
        af = MFMA16(a1, Bf0[1][1], af, 0, 0, 0);
        ag = MFMA16(a1, Bf0[2][1], ag, 0, 0, 0);
        ao = MFMA16(a1, Bf0[3][1], ao, 0, 0, 0);
        ai = MFMA16(a2, Bf0[0][2], ai, 0, 0, 0);
        af = MFMA16(a2, Bf0[1][2], af, 0, 0, 0);
        ag = MFMA16(a2, Bf0[2][2], ag, 0, 0, 0);
        ao = MFMA16(a2, Bf0[3][2], ao, 0, 0, 0);
        unsigned hp[2];
        gates4(ai, af, ag, ao, cc0, hp);
        lds16[wr0]      = (unsigned short)hp[0];
        lds16[wr0 + 8]  = (unsigned short)(hp[0] >> 16);
        lds16[wr0 + 16] = (unsigned short)hp[1];
        lds16[wr0 + 24] = (unsigned short)(hp[1] >> 16);
        BAR();
        rdA ^= A0TOG; wr0 ^= A0TOG; rdH1 ^= A1TOG; wrH1 ^= A1TOG;
    }

    // ---- Steady state it=1..TB-1: one straight-line block, both layers ----
    for (int it = 1; it < TB; ++it) {
        const int ph = it & 63;
        if (ph == 48 && it + 16 < TB) {  // prefetch next chunk -> regs
            const int t0 = (it & ~63) + 64;
            const float* gp = x + (size_t)(rb + srow) * (TB * BD) + t0 * BD + su * 32;
            #pragma unroll
            for (int i = 0; i < 8; ++i) px[i] = ((const float4*)gp)[i];
        }
        if (ph == 62 && it + 2 < TB) {   // pack + write to OTHER XB buffer
            const int t0 = (it & ~63) + 64;
            #pragma unroll
            for (int tt = 0; tt < 4; ++tt) {
                uint4 s;
                s.x = pkbf(px[2*tt].x,   px[2*tt].y);   s.y = pkbf(px[2*tt].z,   px[2*tt].w);
                s.z = pkbf(px[2*tt+1].x, px[2*tt+1].y); s.w = pkbf(px[2*tt+1].z, px[2*tt+1].w);
                const int el = XBASE + ((t0 + su * 4 + tt) & 127) * 128 + srow * 8;
                *(uint4*)(lds16 + el) = s;
            }
        }

        // Shared reads: h0(it-1) feeds L0 recurrence AND L1 input.
        const short8 a0 = *(const short8*)(lds16 + rdA);
        const short8 a1 = *(const short8*)(lds16 + rdA + 512);
        const short8 b2 = *(const short8*)(lds16 + rdH1);        // h1 k 0..31
        const short8 b3 = *(const short8*)(lds16 + rdH1 + 512);  // h1 k 32..63
        const int xaddr = (q == 0) ? (XBASE + ((it & 127) << 7) + ln8) : zaddr;
        const short8 a2 = *(const short8*)(lds16 + xaddr);

        // L0 MFMAs (step t = it)
        f32x4 ai0 = MFMA16(a0, Bf0[0][0], bias0[0], 0, 0, 0);
        f32x4 af0 = MFMA16(a0, Bf0[1][0], bias0[1], 0, 0, 0);
        f32x4 ag0 = MFMA16(a0, Bf0[2][0], bias0[2], 0, 0, 0);
        f32x4 ao0 = MFMA16(a0, Bf0[3][0], bias0[3], 0, 0, 0);
        ai0 = MFMA16(a1, Bf0[0][1], ai0, 0, 0, 0);
        af0 = MFMA16(a1, Bf0[1][1], af0, 0, 0, 0);
        ag0 = MFMA16(a1, Bf0[2][1], ag0, 0, 0, 0);
        ao0 = MFMA16(a1, Bf0[3][1], ao0, 0, 0, 0);
        ai0 = MFMA16(a2, Bf0[0][2], ai0, 0, 0, 0);
        af0 = MFMA16(a2, Bf0[1][2], af0, 0, 0, 0);
        ag0 = MFMA16(a2, Bf0[2][2], ag0, 0, 0, 0);
        ao0 = MFMA16(a2, Bf0[3][2], ao0, 0, 0, 0);

        // L1 MFMAs (step t1 = it-1) — independent of L0's gate chain
        f32x4 ai1 = MFMA16(a0, Bf1[0][0], bias1[0], 0, 0, 0);
        f32x4 af1 = MFMA16(a0, Bf1[1][0], bias1[1], 0, 0, 0);
        f32x4 ag1 = MFMA16(a0, Bf1[2][0], bias1[2], 0, 0, 0);
        f32x4 ao1 = MFMA16(a0, Bf1[3][0], bias1[3], 0, 0, 0);
        ai1 = MFMA16(a1, Bf1[0][1], ai1, 0, 0, 0);
        af1 = MFMA16(a1, Bf1[1][1], af1, 0, 0, 0);
        ag1 = MFMA16(a1, Bf1[2][1], ag1, 0, 0, 0);
        ao1 = MFMA16(a1, Bf1[3][1], ao1, 0, 0, 0);
        ai1 = MFMA16(b2, Bf1[0][2], ai1, 0, 0, 0);
        af1 = MFMA16(b2, Bf1[1][2], af1, 0, 0, 0);
        ag1 = MFMA16(b2, Bf1[2][2], ag1, 0, 0, 0);
        ao1 = MFMA16(b2, Bf1[3][2], ao1, 0, 0, 0);
        ai1 = MFMA16(b3, Bf1[0][3], ai1, 0, 0, 0);
        af1 = MFMA16(b3, Bf1[1][3], af1, 0, 0, 0);
        ag1 = MFMA16(b3, Bf1[2][3], ag1, 0, 0, 0);
        ao1 = MFMA16(b3, Bf1[3][3], ao1, 0, 0, 0);

        unsigned hp0[2], hp1[2];
        gates4(ai0, af0, ag0, ao0, cc0, hp0);
        lds16[wr0]      = (unsigned short)hp0[0];
        lds16[wr0 + 8]  = (unsigned short)(hp0[0] >> 16);
        lds16[wr0 + 16] = (unsigned short)hp0[1];
        lds16[wr0 + 24] = (unsigned short)(hp0[1] >> 16);

        gates4(ai1, af1, ag1, ao1, cc1, hp1);
        lds16[wrH1]      = (unsigned short)hp1[0];
        lds16[wrH1 + 8]  = (unsigned short)(hp1[0] >> 16);
        lds16[wrH1 + 16] = (unsigned short)hp1[1];
        lds16[wrH1 + 24] = (unsigned short)(hp1[1] >> 16);

        BAR();
        rdA ^= A0TOG; wr0 ^= A0TOG; rdH1 ^= A1TOG; wrH1 ^= A1TOG;
    }

    // ---- Peeled it=TB: L1 only (step t1 = TB-1) ----
    {
        const short8 a0 = *(const short8*)(lds16 + rdA);
        const short8 a1 = *(const short8*)(lds16 + rdA + 512);
        const short8 b2 = *(const short8*)(lds16 + rdH1);
        const short8 b3 = *(const short8*)(lds16 + rdH1 + 512);
        f32x4 ai = MFMA16(a0, Bf1[0][0], bias1[0], 0, 0, 0);
        f32x4 af = MFMA16(a0, Bf1[1][0], bias1[1], 0, 0, 0);
        f32x4 ag = MFMA16(a0, Bf1[2][0], bias1[2], 0, 0, 0);
        f32x4 ao = MFMA16(a0, Bf1[3][0], bias1[3], 0, 0, 0);
        ai = MFMA16(a1, Bf1[0][1], ai, 0, 0, 0);
        af = MFMA16(a1, Bf1[1][1], af, 0, 0, 0);
        ag = MFMA16(a1, Bf1[2][1], ag, 0, 0, 0);
        ao = MFMA16(a1, Bf1[3][1], ao, 0, 0, 0);
        ai = MFMA16(b2, Bf1[0][2], ai, 0, 0, 0);
        af = MFMA16(b2, Bf1[1][2], af, 0, 0, 0);
        ag = MFMA16(b2, Bf1[2][2], ag, 0, 0, 0);
        ao = MFMA16(b2, Bf1[3][2], ao, 0, 0, 0);
        ai = MFMA16(b3, Bf1[0][3], ai, 0, 0, 0);
        af = MFMA16(b3, Bf1[1][3], af, 0, 0, 0);
        ag = MFMA16(b3, Bf1[2][3], ag, 0, 0, 0);
        ao = MFMA16(b3, Bf1[3][3], ao, 0, 0, 0);
        unsigned hp[2];
        gates4(ai, af, ag, ao, cc1, hp);
        lds16[wrH1]      = (unsigned short)hp[0];
        lds16[wrH1 + 8]  = (unsigned short)(hp[0] >> 16);
        lds16[wrH1 + 16] = (unsigned short)hp[1];
        lds16[wrH1 + 24] = (unsigned short)(hp[1] >> 16);
        BAR();
    }

    // Final FC: h1(511) written at it=512 -> A1 parity 1
    if (tid < BSL) {
        float s = bfc[0];
        #pragma unroll 8
        for (int j = 0; j < 64; ++j)
            s += bf2f(lds16[A1BASE + A1TOG + (j >> 3) * 128 + tid * 8 + (j & 7)]) * Wfc[j];
        out[rb + tid] = s;
    }
}

extern "C" void kernel_launch(void* const* d_in, const int* in_sizes, int n_in,
                              void* d_out, int out_size, void* d_ws, size_t ws_size,
                              hipStream_t stream) {
    const float* x    = (const float*)d_in[0];
    const float* Wih0 = (const float*)d_in[1];
    const float* Whh0 = (const float*)d_in[2];
    const float* bih0 = (const float*)d_in[3];
    const float* bhh0 = (const float*)d_in[4];
    const float* Wih1 = (const float*)d_in[5];
    const float* Whh1 = (const float*)d_in[6];
    const float* bih1 = (const float*)d_in[7];
    const float* bhh1 = (const float*)d_in[8];
    const float* Wfc  = (const float*)d_in[9];
    const float* bfc  = (const float*)d_in[10];
    float* out = (float*)d_out;

    dim3 grid(BTOT / BSL);   // 256 blocks = 1 per CU
    dim3 block(256);         // 4 waves: each owns 16 hidden cols, BOTH layers
    lstm2_fused<<<grid, block, 0, stream>>>(x, Wih0, Whh0, bih0, bhh0,
                                            Wih1, Whh1, bih1, bhh1, Wfc, bfc, out);
}